// Round 1
// baseline (394.179 us; speedup 1.0000x reference)
//
#include <hip/hip_runtime.h>

// ISDLoss_only_type1: masked symmetric KL between mixed conf and interpolation.
// B=128, N=8732, C=21; fp32 in, scalar fp32 out.
//
// R2 (prev): LDS-staged tiles, coalesced f4 loads. 107us main kernel; 65KB LDS
//            -> 2 blocks/CU -> 20% occupancy -> latency-bound (16% HBM, 22% VALU).
// R3: register-resident rows. 4 rows = 84 floats = exactly 21 float4 (336B,
//     16B-aligned; N%4==0 so a 4-row group never straddles the batch swap).
//     One thread owns 4 whole rows: 21x3 f4 loads fully unrolled, row/class
//     indices compile-time. No LDS data staging, no barriers in the hot path.

#define EPS 1e-7f

constexpr int B = 128;
constexpr int N = 8732;
constexpr int C = 21;
constexpr int ROWS = B * N;                    // 1,117,696
constexpr int RPT = 4;                         // rows per thread (21 float4)
constexpr int GROUPS = ROWS / RPT;             // 279,424
constexpr int BLOCK = 256;
constexpr int GRID = (GROUPS + BLOCK - 1) / BLOCK;   // 1092 (last block half-full)
constexpr int F4_PER_GROUP = RPT * C / 4;      // 21
constexpr int BATCH_F4 = (N * C) / 4;          // 45,843
constexpr int GROUPS_PER_BATCH = N / RPT;      // 2,183

__global__ __launch_bounds__(BLOCK, 4) void isd_main_kernel(
    const float* __restrict__ lam_p,
    const float* __restrict__ conf,
    const float* __restrict__ csh,   // conf_shuffle
    const float* __restrict__ cin,   // conf_interpolation
    double* __restrict__ partials)   // [2*GRID]: (sum, cnt) per block
{
    const int gid = blockIdx.x * BLOCK + threadIdx.x;

    double bs = 0.0, bc = 0.0;

    if (gid < GROUPS) {
        const float4* conf4 = (const float4*)conf;
        const float4* csh4  = (const float4*)csh;
        const float4* cin4  = (const float4*)cin;

        // batch-half swap: conf_temp[b] = csh[b ^ 64]; all 4 rows share b.
        const int b     = gid / GROUPS_PER_BATCH;
        const int base  = gid * F4_PER_GROUP;
        const int base2 = base + ((b ^ 64) - b) * BATCH_F4;

        const float lam = lam_p[0];
        const float oml = 1.0f - lam;

        float kl[RPT]   = {0.0f, 0.0f, 0.0f, 0.0f};
        float c0[RPT], t0[RPT], cmax[RPT], tmax[RPT];

        #pragma unroll
        for (int j = 0; j < F4_PER_GROUP; ++j) {
            const float4 cf = conf4[base  + j];
            const float4 tf = csh4 [base2 + j];
            const float4 vf = cin4 [base  + j];
            const float* cp = (const float*)&cf;
            const float* tp = (const float*)&tf;
            const float* ip = (const float*)&vf;
            #pragma unroll
            for (int e = 0; e < 4; ++e) {
                const int idx = 4 * j + e;       // 0..83, compile-time
                const int r   = idx / C;         // row within group
                const int c   = idx % C;         // class
                const float cv = cp[e];
                const float tv = tp[e];
                const float iv = ip[e] + EPS;
                const float mv = fmaf(lam, cv, oml * tv) + EPS;
                // kl_a + kl_b per class: iv*(li-lm) + mv*(lm-li) == (iv-mv)*(li-lm)
                kl[r] += (iv - mv) * (__logf(iv) - __logf(mv));
                if (c == 0) {
                    c0[r] = cv; t0[r] = tv;
                    cmax[r] = -1e30f; tmax[r] = -1e30f;
                } else {
                    cmax[r] = fmaxf(cmax[r], cv);
                    tmax[r] = fmaxf(tmax[r], tv);
                }
            }
        }

        #pragma unroll
        for (int r = 0; r < RPT; ++r) {
            if ((cmax[r] > c0[r]) && (tmax[r] > t0[r])) {
                bs += (double)kl[r];
                bc += 1.0;
            }
        }
    }

    // ---- reduce: wave shuffle (doubles) -> LDS -> per-block double partial ----
    #pragma unroll
    for (int off = 32; off > 0; off >>= 1) {
        bs += __shfl_down(bs, off, 64);
        bc += __shfl_down(bc, off, 64);
    }

    __shared__ double r_sum[BLOCK / 64];
    __shared__ double r_cnt[BLOCK / 64];
    const int wave = threadIdx.x >> 6;
    const int lane = threadIdx.x & 63;
    if (lane == 0) { r_sum[wave] = bs; r_cnt[wave] = bc; }
    __syncthreads();

    if (threadIdx.x == 0) {
        double s = 0.0, c = 0.0;
        #pragma unroll
        for (int w = 0; w < BLOCK / 64; ++w) { s += r_sum[w]; c += r_cnt[w]; }
        partials[2 * blockIdx.x + 0] = s;
        partials[2 * blockIdx.x + 1] = c;
    }
}

__global__ __launch_bounds__(256) void isd_final_kernel(
    const double* __restrict__ partials,
    float* __restrict__ out)
{
    double s = 0.0, c = 0.0;
    for (int i = threadIdx.x; i < GRID; i += 256) {
        s += partials[2 * i + 0];
        c += partials[2 * i + 1];
    }
    #pragma unroll
    for (int off = 32; off > 0; off >>= 1) {
        s += __shfl_down(s, off, 64);
        c += __shfl_down(c, off, 64);
    }
    __shared__ double ss[4], sc[4];
    const int wave = threadIdx.x >> 6;
    const int lane = threadIdx.x & 63;
    if (lane == 0) { ss[wave] = s; sc[wave] = c; }
    __syncthreads();
    if (threadIdx.x == 0) {
        const double S  = ss[0] + ss[1] + ss[2] + ss[3];
        const double Cc = sc[0] + sc[1] + sc[2] + sc[3];
        out[0] = (Cc > 0.0) ? (float)(S / fmax(Cc, 1.0) * 0.5) : 0.0f;
    }
}

extern "C" void kernel_launch(void* const* d_in, const int* in_sizes, int n_in,
                              void* d_out, int out_size, void* d_ws, size_t ws_size,
                              hipStream_t stream) {
    const float* lam  = (const float*)d_in[0];
    const float* conf = (const float*)d_in[1];
    const float* csh  = (const float*)d_in[2];
    const float* cin  = (const float*)d_in[3];
    float* out = (float*)d_out;
    double* partials = (double*)d_ws;   // 2*GRID doubles = ~17.5 KB

    isd_main_kernel<<<GRID, BLOCK, 0, stream>>>(lam, conf, csh, cin, partials);
    isd_final_kernel<<<1, 256, 0, stream>>>(partials, out);
}

// Round 2
// 269.113 us; speedup vs baseline: 1.4647x; 1.4647x over previous
//
#include <hip/hip_runtime.h>

// ISDLoss_only_type1: masked symmetric KL between mixed conf and interpolation.
// B=128, N=8732, C=21; fp32 in, scalar fp32 out.
//
// R2: LDS-staged tiles. 107us main; 65KB LDS -> 8 waves/CU -> latency-bound.
// R3: per-lane register rows (336B/lane). FETCH 687MB (2.4x inputs!) -- per-lane
//     chunks thrash L1/L2/L3 (64.5KB live set per wave * ~12 waves/CU * 256 CU),
//     so the line reuse across unrolled js missed. 228us. REVERTED.
// R4: wave-cooperative rows. 3 rows = 63 floats per wave-iter; lane l owns
//     class l%21 of row l/21. Every load is 64x4B contiguous (one 256B
//     transaction, fully consumed by its own instruction -> no cache reliance).
//     Row reductions in-wave: guarded shfl tree for sum-KL, __ballot + 21-bit
//     window for the two foreground tests. Batch-half swap = e +- HALF_ELEMS.
//     No LDS in hot path -> occupancy VGPR-limited only.

#define EPS 1e-7f

constexpr int B = 128;
constexpr int N = 8732;
constexpr int C = 21;
constexpr int ROWS = B * N;                  // 1,117,696
constexpr int ELEMS = ROWS * C;              // 23,471,616
constexpr int HALF_ELEMS = (B / 2) * N * C;  // 11,735,808
constexpr int RPI = 3;                       // rows per wave-iteration
constexpr int GELEMS = RPI * C;              // 63 active lanes
constexpr int NGROUPS = (ROWS + RPI - 1) / RPI;  // 372,566
constexpr int BLOCK = 256;
constexpr int GRID = 2048;                   // 8 blocks/CU target
constexpr int NWAVES = GRID * (BLOCK / 64);  // 8192

__global__ __launch_bounds__(BLOCK, 6) void isd_main_kernel(
    const float* __restrict__ lam_p,
    const float* __restrict__ conf,
    const float* __restrict__ csh,   // conf_shuffle
    const float* __restrict__ cin,   // conf_interpolation
    double* __restrict__ partials)   // [2*GRID]: (sum, cnt) per block
{
    const int tid  = threadIdx.x;
    const int lane = tid & 63;
    const int wid  = (blockIdx.x * BLOCK + tid) >> 6;   // global wave id

    const int dr    = lane / 21;          // row within group: 0,1,2 (lane 63 -> 3)
    const int cpos  = lane - dr * 21;     // class index 0..20
    const int gbase = dr * 21;            // first lane of my row-group (63 for lane 63)
    const unsigned long long gm = 0x1FFFFFull;  // 21 bits

    const float lam = lam_p[0];
    const float oml = 1.0f - lam;

    double bs = 0.0, bc = 0.0;

    for (int g = wid; g < NGROUPS; g += NWAVES) {
        const int e     = g * GELEMS + lane;            // element index (row*21 + c)
        const bool valid = (lane < GELEMS) && (e < ELEMS);
        const int ec    = valid ? e : (ELEMS - 1);      // clamped, always in-bounds

        // coalesced: 64 lanes x 4B contiguous per load
        const float cv  = conf[ec];
        const float ivr = cin[ec];
        const int e2    = ec + ((ec < HALF_ELEMS) ? HALF_ELEMS : -HALF_ELEMS);
        const float tv  = csh[e2];

        const float iv = ivr + EPS;
        const float mv = fmaf(lam, cv, oml * tv) + EPS;
        // kl_a + kl_b per class: iv*(li-lm) + mv*(lm-li) == (iv-mv)*(li-lm)
        float klt = (iv - mv) * (__logf(iv) - __logf(mv));
        klt = valid ? klt : 0.0f;

        // broadcast background score (class 0) of my row to all 21 lanes
        const float c0 = __shfl(cv, gbase, 64);
        const float t0 = __shfl(tv, gbase, 64);
        // foreground tests: any class 1..20 beats class 0 (cpos==0 lane compares
        // cv>cv == false, so its own bit is harmlessly 0)
        const unsigned long long balc = __ballot(cv > c0);
        const unsigned long long balt = __ballot(tv > t0);

        // guarded tree-sum of klt over the 21 lanes of my row -> lands on cpos==0
        #pragma unroll
        for (int off = 16; off > 0; off >>= 1) {
            const float o = __shfl(klt, lane + off, 64);
            if (cpos + off < 21) klt += o;
        }

        if (cpos == 0 && valid) {
            const bool fg = (((balc >> lane) & gm) != 0ull) &&
                            (((balt >> lane) & gm) != 0ull);
            if (fg) { bs += (double)klt; bc += 1.0; }
        }
    }

    // ---- reduce: wave shuffle (doubles) -> LDS -> per-block double partial ----
    #pragma unroll
    for (int off = 32; off > 0; off >>= 1) {
        bs += __shfl_down(bs, off, 64);
        bc += __shfl_down(bc, off, 64);
    }

    __shared__ double r_sum[BLOCK / 64];
    __shared__ double r_cnt[BLOCK / 64];
    const int wave = tid >> 6;
    if ((tid & 63) == 0) { r_sum[wave] = bs; r_cnt[wave] = bc; }
    __syncthreads();

    if (tid == 0) {
        double s = 0.0, c = 0.0;
        #pragma unroll
        for (int w = 0; w < BLOCK / 64; ++w) { s += r_sum[w]; c += r_cnt[w]; }
        partials[2 * blockIdx.x + 0] = s;
        partials[2 * blockIdx.x + 1] = c;
    }
}

__global__ __launch_bounds__(256) void isd_final_kernel(
    const double* __restrict__ partials,
    float* __restrict__ out)
{
    double s = 0.0, c = 0.0;
    for (int i = threadIdx.x; i < GRID; i += 256) {
        s += partials[2 * i + 0];
        c += partials[2 * i + 1];
    }
    #pragma unroll
    for (int off = 32; off > 0; off >>= 1) {
        s += __shfl_down(s, off, 64);
        c += __shfl_down(c, off, 64);
    }
    __shared__ double ss[4], sc[4];
    const int wave = threadIdx.x >> 6;
    const int lane = threadIdx.x & 63;
    if (lane == 0) { ss[wave] = s; sc[wave] = c; }
    __syncthreads();
    if (threadIdx.x == 0) {
        const double S  = ss[0] + ss[1] + ss[2] + ss[3];
        const double Cc = sc[0] + sc[1] + sc[2] + sc[3];
        out[0] = (Cc > 0.0) ? (float)(S / fmax(Cc, 1.0) * 0.5) : 0.0f;
    }
}

extern "C" void kernel_launch(void* const* d_in, const int* in_sizes, int n_in,
                              void* d_out, int out_size, void* d_ws, size_t ws_size,
                              hipStream_t stream) {
    const float* lam  = (const float*)d_in[0];
    const float* conf = (const float*)d_in[1];
    const float* csh  = (const float*)d_in[2];
    const float* cin  = (const float*)d_in[3];
    float* out = (float*)d_out;
    double* partials = (double*)d_ws;   // 2*GRID doubles = 32 KB

    isd_main_kernel<<<GRID, BLOCK, 0, stream>>>(lam, conf, csh, cin, partials);
    isd_final_kernel<<<1, 256, 0, stream>>>(partials, out);
}